// Round 1
// baseline (630.965 us; speedup 1.0000x reference)
//
#include <hip/hip_runtime.h>

typedef __attribute__((ext_vector_type(8))) short short8;
typedef __attribute__((ext_vector_type(4))) float floatx4;

__device__ __forceinline__ unsigned short f2bf(float f) {
  union { float f; unsigned int u; } x; x.f = f;
  unsigned int r = (x.u + 0x7fffu + ((x.u >> 16) & 1u)) >> 16;
  return (unsigned short)r;
}

__device__ __forceinline__ void gload_lds16(const void* g, void* l) {
  __builtin_amdgcn_global_load_lds((const __attribute__((address_space(1))) void*)g,
                                   (__attribute__((address_space(3))) void*)l,
                                   16, 0, 0);
}

// ---------------------------------------------------------------------------
// Prep: densify masked weights to bf16. Wc = (Wl*mask)@(Wq*mask) (<=81 nnz/row),
// Wk_d/Wv_d = masked rows (25 nnz), bqe = (Wl*mask)@bq.  side=32, H=1024.
// ---------------------------------------------------------------------------
__global__ __launch_bounds__(128) void prep_weights(
    const float* __restrict__ Wq, const float* __restrict__ Wk,
    const float* __restrict__ Wv, const float* __restrict__ Wl,
    const float* __restrict__ bq,
    unsigned short* __restrict__ Wc_d, unsigned short* __restrict__ Wk_d,
    unsigned short* __restrict__ Wv_d, float* __restrict__ bqe) {
  const int i = blockIdx.x;
  const int r = i >> 5, c = i & 31;
  const int t = threadIdx.x;
  for (int p = t; p < 1024; p += 128) {
    Wc_d[i * 1024 + p] = 0; Wk_d[i * 1024 + p] = 0; Wv_d[i * 1024 + p] = 0;
  }
  __syncthreads();
  if (t < 25) {
    int dr = t / 5 - 2, dc = t % 5 - 2;
    int j = (((r + dr) & 31) << 5) | ((c + dc) & 31);
    Wk_d[i * 1024 + j] = f2bf(Wk[i * 1024 + j]);
    Wv_d[i * 1024 + j] = f2bf(Wv[i * 1024 + j]);
  }
  if (t < 81) {
    int dr = t / 9 - 4, dc = t % 9 - 4;
    int j = (((r + dr) & 31) << 5) | ((c + dc) & 31);
    float s = 0.f;
    int erlo = dr - 2 < -2 ? -2 : dr - 2, erhi = dr + 2 > 2 ? 2 : dr + 2;
    int eclo = dc - 2 < -2 ? -2 : dc - 2, echi = dc + 2 > 2 ? 2 : dc + 2;
    for (int er = erlo; er <= erhi; ++er)
      for (int ec = eclo; ec <= echi; ++ec) {
        int m = (((r + er) & 31) << 5) | ((c + ec) & 31);
        s += Wl[i * 1024 + m] * Wq[m * 1024 + j];
      }
    Wc_d[i * 1024 + j] = f2bf(s);
  }
  if (t == 96) {
    float s = 0.f;
    for (int e = 0; e < 25; ++e) {
      int dr = e / 5 - 2, dc = e % 5 - 2;
      int m = (((r + dr) & 31) << 5) | ((c + dc) & 31);
      s += Wl[i * 1024 + m] * bq[m];
    }
    bqe[i] = s;
  }
}

// ---------------------------------------------------------------------------
// Cast x (fp32) -> bf16, 4 elems/thread
// ---------------------------------------------------------------------------
__global__ __launch_bounds__(256) void cast_bf16(const float4* __restrict__ x,
                                                 ushort4* __restrict__ xb) {
  int i = blockIdx.x * 256 + threadIdx.x;
  float4 v = x[i];
  ushort4 o;
  o.x = f2bf(v.x); o.y = f2bf(v.y); o.z = f2bf(v.z); o.w = f2bf(v.w);
  xb[i] = o;
}

// ---------------------------------------------------------------------------
// m97-style GEMM: C[m,n] = scale * sum_k A[m,k]*B[n,k] (+bias[n], bf16 out)
// 128x128 tile, BK=64, 4 waves in 2x2, 16x16x32 bf16 MFMA.
// LDS: [row][8 granules of 16B], granule position XOR-swizzled with (row&7)
// (global_load_lds forces lane-contiguous LDS, so swizzle replaces padding).
// OUTMODE 0: bf16 out + fp32 bias.  OUTMODE 1: fp32 out * scale.
// ---------------------------------------------------------------------------
template <int OUTMODE>
__global__ __launch_bounds__(256, 2) void gemm_bt(
    const unsigned short* __restrict__ A, const unsigned short* __restrict__ B,
    void* __restrict__ Cv, const float* __restrict__ bias,
    int lda, int ldb, int ldc, int K, float scale,
    size_t sA, size_t sB, size_t sC) {
  __shared__ unsigned short lA[128 * 64];
  __shared__ unsigned short lB[128 * 64];
  const int t = threadIdx.x;
  const int lane = t & 63;
  const int wv = t >> 6;
  const int wm = wv >> 1, wn = wv & 1;
  const int l15 = lane & 15, lq = lane >> 4;
  const int bm = blockIdx.y, bn = blockIdx.x, bz = blockIdx.z;
  A += sA * bz; B += sB * bz;

  floatx4 acc[4][4];
#pragma unroll
  for (int i = 0; i < 4; ++i)
#pragma unroll
    for (int j = 0; j < 4; ++j) acc[i][j] = (floatx4){0.f, 0.f, 0.f, 0.f};

  for (int kt = 0; kt < K; kt += 64) {
    __syncthreads();
#pragma unroll
    for (int c = 0; c < 4; ++c) {
      int slot = c * 256 + t;
      int r = slot >> 3, gp = slot & 7;
      int gd = gp ^ (r & 7);
      gload_lds16(A + (size_t)(bm * 128 + r) * lda + kt + gd * 8,
                  &lA[(size_t)(c * 256 + (t & 192)) * 8]);
      gload_lds16(B + (size_t)(bn * 128 + r) * ldb + kt + gd * 8,
                  &lB[(size_t)(c * 256 + (t & 192)) * 8]);
    }
    __syncthreads();
#pragma unroll
    for (int s = 0; s < 2; ++s) {
      short8 aF[4], bF[4];
#pragma unroll
      for (int i = 0; i < 4; ++i) {
        int rowA = wm * 64 + i * 16 + l15;
        int g = s * 4 + lq;
        aF[i] = *(const short8*)&lA[rowA * 64 + ((g ^ (rowA & 7)) << 3)];
        int rowB = wn * 64 + i * 16 + l15;
        bF[i] = *(const short8*)&lB[rowB * 64 + ((g ^ (rowB & 7)) << 3)];
      }
#pragma unroll
      for (int i = 0; i < 4; ++i)
#pragma unroll
        for (int j = 0; j < 4; ++j)
          acc[i][j] = __builtin_amdgcn_mfma_f32_16x16x32_bf16(aF[i], bF[j],
                                                              acc[i][j], 0, 0, 0);
    }
  }

  const int row0 = bm * 128 + wm * 64;
  const int col0 = bn * 128 + wn * 64;
  if (OUTMODE == 0) {
    unsigned short* C = (unsigned short*)Cv + sC * bz;
#pragma unroll
    for (int i = 0; i < 4; ++i)
#pragma unroll
      for (int j = 0; j < 4; ++j) {
        int col = col0 + j * 16 + l15;
        float bb = bias[col];
#pragma unroll
        for (int r2 = 0; r2 < 4; ++r2) {
          int row = row0 + i * 16 + (lq << 2) + r2;
          C[(size_t)row * ldc + col] = f2bf(acc[i][j][r2] + bb);
        }
      }
  } else {
    float* C = (float*)Cv + sC * bz;
#pragma unroll
    for (int i = 0; i < 4; ++i)
#pragma unroll
      for (int j = 0; j < 4; ++j) {
        int col = col0 + j * 16 + l15;
#pragma unroll
        for (int r2 = 0; r2 < 4; ++r2) {
          int row = row0 + i * 16 + (lq << 2) + r2;
          C[(size_t)row * ldc + col] = acc[i][j][r2] * scale;
        }
      }
  }
}

// ---------------------------------------------------------------------------
// v [B*S][H] bf16 -> vT [B][H][S] bf16
// ---------------------------------------------------------------------------
__global__ __launch_bounds__(1024) void transpose_v(const unsigned short* __restrict__ v,
                                                    unsigned short* __restrict__ vT) {
  __shared__ unsigned short tile[32][33];
  int s0 = blockIdx.x * 32, h0 = blockIdx.y * 32, b = blockIdx.z;
  int tx = threadIdx.x, ty = threadIdx.y;
  tile[ty][tx] = v[((size_t)b * 2048 + s0 + ty) * 1024 + h0 + tx];
  __syncthreads();
  vT[((size_t)b * 1024 + h0 + ty) * 2048 + s0 + tx] = tile[tx][ty];
}

// ---------------------------------------------------------------------------
// Row softmax over 2048 elems, in-place fp32, plus bf16 copy for the PV GEMM.
// One block (256 thr) per row, 8 elems/thread.
// ---------------------------------------------------------------------------
__global__ __launch_bounds__(256) void softmax_rows(float* __restrict__ probs,
                                                    unsigned short* __restrict__ pb) {
  const size_t row = blockIdx.x;
  float4* p = (float4*)(probs + row * 2048);
  const int t = threadIdx.x;
  float4 v0 = p[t];
  float4 v1 = p[256 + t];
  float m = fmaxf(fmaxf(fmaxf(v0.x, v0.y), fmaxf(v0.z, v0.w)),
                  fmaxf(fmaxf(v1.x, v1.y), fmaxf(v1.z, v1.w)));
  for (int o = 32; o; o >>= 1) m = fmaxf(m, __shfl_xor(m, o));
  __shared__ float red[8];
  if ((t & 63) == 0) red[t >> 6] = m;
  __syncthreads();
  m = fmaxf(fmaxf(red[0], red[1]), fmaxf(red[2], red[3]));
  v0.x = __expf(v0.x - m); v0.y = __expf(v0.y - m);
  v0.z = __expf(v0.z - m); v0.w = __expf(v0.w - m);
  v1.x = __expf(v1.x - m); v1.y = __expf(v1.y - m);
  v1.z = __expf(v1.z - m); v1.w = __expf(v1.w - m);
  float s = v0.x + v0.y + v0.z + v0.w + v1.x + v1.y + v1.z + v1.w;
  for (int o = 32; o; o >>= 1) s += __shfl_xor(s, o);
  if ((t & 63) == 0) red[4 + (t >> 6)] = s;
  __syncthreads();
  s = red[4] + red[5] + red[6] + red[7];
  float inv = 1.0f / s;
  v0.x *= inv; v0.y *= inv; v0.z *= inv; v0.w *= inv;
  v1.x *= inv; v1.y *= inv; v1.z *= inv; v1.w *= inv;
  p[t] = v0; p[256 + t] = v1;
  ushort4* pbv = (ushort4*)(pb + row * 2048);
  ushort4 o0, o1;
  o0.x = f2bf(v0.x); o0.y = f2bf(v0.y); o0.z = f2bf(v0.z); o0.w = f2bf(v0.w);
  o1.x = f2bf(v1.x); o1.y = f2bf(v1.y); o1.z = f2bf(v1.z); o1.w = f2bf(v1.w);
  pbv[t] = o0; pbv[256 + t] = o1;
}

// ---------------------------------------------------------------------------
extern "C" void kernel_launch(void* const* d_in, const int* in_sizes, int n_in,
                              void* d_out, int out_size, void* d_ws, size_t ws_size,
                              hipStream_t stream) {
  const float* x  = (const float*)d_in[0];
  const float* Wq = (const float*)d_in[1];
  const float* bq = (const float*)d_in[2];
  const float* Wk = (const float*)d_in[3];
  const float* bk = (const float*)d_in[4];
  const float* Wv = (const float*)d_in[5];
  const float* bv = (const float*)d_in[6];
  const float* Wl = (const float*)d_in[7];

  const int B = 8, S = 2048, H = 1024;
  float* out   = (float*)d_out;                   // [B,S,H]
  float* probs = (float*)d_out + (size_t)B * S * H; // [B,S,S]

  char* ws = (char*)d_ws;
  // layout (bytes): pb overlays xb+vb (dead by softmax time)
  unsigned short* xb   = (unsigned short*)(ws + 0);           // 33.5MB [B*S][H]
  unsigned short* vb   = (unsigned short*)(ws + 33554432);    // 33.5MB [B*S][H]
  unsigned short* pb   = (unsigned short*)(ws + 0);           // 67MB   [B*S][S]
  unsigned short* qb   = (unsigned short*)(ws + 67108864);    // 33.5MB
  unsigned short* kb   = (unsigned short*)(ws + 100663296);   // 33.5MB
  unsigned short* vT   = (unsigned short*)(ws + 134217728);   // 33.5MB [B][H][S]
  unsigned short* Wc_d = (unsigned short*)(ws + 167772160);   // 2MB
  unsigned short* Wk_d = (unsigned short*)(ws + 169869312);   // 2MB
  unsigned short* Wv_d = (unsigned short*)(ws + 171966464);   // 2MB
  float*          bqe  = (float*)(ws + 174063616);            // 4KB

  prep_weights<<<1024, 128, 0, stream>>>(Wq, Wk, Wv, Wl, bq, Wc_d, Wk_d, Wv_d, bqe);
  cast_bf16<<<16384, 256, 0, stream>>>((const float4*)x, (ushort4*)xb);

  // projections: q = x@Wc^T + bqe ; k = x@Wkm^T + bk ; v = x@Wvm^T + bv
  gemm_bt<0><<<dim3(8, 128, 1), 256, 0, stream>>>(xb, Wc_d, qb, bqe, H, H, H, H, 1.f, 0, 0, 0);
  gemm_bt<0><<<dim3(8, 128, 1), 256, 0, stream>>>(xb, Wk_d, kb, bk,  H, H, H, H, 1.f, 0, 0, 0);
  gemm_bt<0><<<dim3(8, 128, 1), 256, 0, stream>>>(xb, Wv_d, vb, bv,  H, H, H, H, 1.f, 0, 0, 0);

  transpose_v<<<dim3(64, 32, 8), dim3(32, 32), 0, stream>>>(vb, vT);

  // scores = q @ k^T / 32  -> probs region (raw)
  gemm_bt<1><<<dim3(16, 16, 8), 256, 0, stream>>>(qb, kb, probs, nullptr,
      H, H, S, H, 1.0f / 32.0f, (size_t)S * H, (size_t)S * H, (size_t)S * S);

  softmax_rows<<<16384, 256, 0, stream>>>(probs, pb);

  // out = probs @ v   (B operand = vT, k-major over t)
  gemm_bt<1><<<dim3(8, 16, 8), 256, 0, stream>>>(pb, vT, out, nullptr,
      S, S, H, S, 1.0f, (size_t)S * S, (size_t)H * S, (size_t)S * H);
}

// Round 2
// 570.514 us; speedup vs baseline: 1.1060x; 1.1060x over previous
//
#include <hip/hip_runtime.h>

typedef __attribute__((ext_vector_type(8))) short short8;
typedef __attribute__((ext_vector_type(4))) float floatx4;

__device__ __forceinline__ unsigned short f2bf(float f) {
  union { float f; unsigned int u; } x; x.f = f;
  unsigned int r = (x.u + 0x7fffu + ((x.u >> 16) & 1u)) >> 16;
  return (unsigned short)r;
}
__device__ __forceinline__ float bf2f(unsigned short u) {
  union { unsigned int u; float f; } x; x.u = ((unsigned int)u) << 16;
  return x.f;
}

__device__ __forceinline__ void gload_lds16(const void* g, void* l) {
  __builtin_amdgcn_global_load_lds((const __attribute__((address_space(1))) void*)g,
                                   (__attribute__((address_space(3))) void*)l,
                                   16, 0, 0);
}

// ---------------------------------------------------------------------------
// Prep: densify masked weights to bf16 into one [3072][1024] Wqkv buffer:
// rows 0-1023 = Wc = (Wl*mask)@(Wq*mask) (<=81 nnz/row), 1024+ = Wk*mask,
// 2048+ = Wv*mask (25 nnz). biasAll[3072] = [ (Wl*mask)@bq | bk | bv ].
// ---------------------------------------------------------------------------
__global__ __launch_bounds__(128) void prep_weights(
    const float* __restrict__ Wq, const float* __restrict__ Wk,
    const float* __restrict__ Wv, const float* __restrict__ Wl,
    const float* __restrict__ bq, const float* __restrict__ bk,
    const float* __restrict__ bv,
    unsigned short* __restrict__ Wqkv, float* __restrict__ biasAll) {
  const int i = blockIdx.x;
  const int r = i >> 5, c = i & 31;
  const int t = threadIdx.x;
  for (int p = t; p < 1024; p += 128) {
    Wqkv[i * 1024 + p] = 0;
    Wqkv[(1024 + i) * 1024 + p] = 0;
    Wqkv[(2048 + i) * 1024 + p] = 0;
  }
  __syncthreads();
  if (t < 25) {
    int dr = t / 5 - 2, dc = t % 5 - 2;
    int j = (((r + dr) & 31) << 5) | ((c + dc) & 31);
    Wqkv[(1024 + i) * 1024 + j] = f2bf(Wk[i * 1024 + j]);
    Wqkv[(2048 + i) * 1024 + j] = f2bf(Wv[i * 1024 + j]);
  }
  if (t < 81) {
    int dr = t / 9 - 4, dc = t % 9 - 4;
    int j = (((r + dr) & 31) << 5) | ((c + dc) & 31);
    float s = 0.f;
    int erlo = dr - 2 < -2 ? -2 : dr - 2, erhi = dr + 2 > 2 ? 2 : dr + 2;
    int eclo = dc - 2 < -2 ? -2 : dc - 2, echi = dc + 2 > 2 ? 2 : dc + 2;
    for (int er = erlo; er <= erhi; ++er)
      for (int ec = eclo; ec <= echi; ++ec) {
        int m = (((r + er) & 31) << 5) | ((c + ec) & 31);
        s += Wl[i * 1024 + m] * Wq[m * 1024 + j];
      }
    Wqkv[i * 1024 + j] = f2bf(s);
  }
  if (t == 96) {
    float s = 0.f;
    for (int e = 0; e < 25; ++e) {
      int dr = e / 5 - 2, dc = e % 5 - 2;
      int m = (((r + dr) & 31) << 5) | ((c + dc) & 31);
      s += Wl[i * 1024 + m] * bq[m];
    }
    biasAll[i] = s;
  }
  if (t == 97) biasAll[1024 + i] = bk[i];
  if (t == 98) biasAll[2048 + i] = bv[i];
}

// ---------------------------------------------------------------------------
__global__ __launch_bounds__(256) void cast_bf16(const float4* __restrict__ x,
                                                 ushort4* __restrict__ xb) {
  int i = blockIdx.x * 256 + threadIdx.x;
  float4 v = x[i];
  ushort4 o;
  o.x = f2bf(v.x); o.y = f2bf(v.y); o.z = f2bf(v.z); o.w = f2bf(v.w);
  xb[i] = o;
}

// ---------------------------------------------------------------------------
// m97-style GEMM: C[m,n] = sum_k A[m,k]*B[n,k]; 128x128 tile, BK=64,
// 4 waves 2x2, 16x16x32 bf16 MFMA, global_load_lds w=16, XOR-swizzled LDS.
// OUTMODE 0: bf16 out + fp32 bias[col] (QKV projection)
// OUTMODE 2: scores->exp fused: e=exp(acc*scale) bf16 out; per-row partial
//            sums of e over this 128-col block -> Lpart[row*16 + bn]
// OUTMODE 3: fp32 out * invL[row] (PV with deferred softmax normalization)
// ---------------------------------------------------------------------------
template <int OUTMODE>
__global__ __launch_bounds__(256, 2) void gemm_bt(
    const unsigned short* __restrict__ A, const unsigned short* __restrict__ B,
    void* __restrict__ Cv, const float* __restrict__ auxc, float* __restrict__ auxw,
    int lda, int ldb, int ldc, int K, float scale,
    size_t sA, size_t sB, size_t sC) {
  __shared__ unsigned short lA[128 * 64];
  __shared__ unsigned short lB[128 * 64];
  __shared__ float sred[2][128];
  const int t = threadIdx.x;
  const int lane = t & 63;
  const int wv = t >> 6;
  const int wm = wv >> 1, wn = wv & 1;
  const int l15 = lane & 15, lq = lane >> 4;
  const int bm = blockIdx.y, bn = blockIdx.x, bz = blockIdx.z;
  A += sA * bz; B += sB * bz;

  floatx4 acc[4][4];
#pragma unroll
  for (int i = 0; i < 4; ++i)
#pragma unroll
    for (int j = 0; j < 4; ++j) acc[i][j] = (floatx4){0.f, 0.f, 0.f, 0.f};

  for (int kt = 0; kt < K; kt += 64) {
    __syncthreads();
#pragma unroll
    for (int c = 0; c < 4; ++c) {
      int slot = c * 256 + t;
      int r = slot >> 3, gp = slot & 7;
      int gd = gp ^ (r & 7);
      gload_lds16(A + (size_t)(bm * 128 + r) * lda + kt + gd * 8,
                  &lA[(size_t)(c * 256 + (t & 192)) * 8]);
      gload_lds16(B + (size_t)(bn * 128 + r) * ldb + kt + gd * 8,
                  &lB[(size_t)(c * 256 + (t & 192)) * 8]);
    }
    __syncthreads();
#pragma unroll
    for (int s = 0; s < 2; ++s) {
      short8 aF[4], bF[4];
#pragma unroll
      for (int i = 0; i < 4; ++i) {
        int rowA = wm * 64 + i * 16 + l15;
        int g = s * 4 + lq;
        aF[i] = *(const short8*)&lA[rowA * 64 + ((g ^ (rowA & 7)) << 3)];
        int rowB = wn * 64 + i * 16 + l15;
        bF[i] = *(const short8*)&lB[rowB * 64 + ((g ^ (rowB & 7)) << 3)];
      }
#pragma unroll
      for (int i = 0; i < 4; ++i)
#pragma unroll
        for (int j = 0; j < 4; ++j)
          acc[i][j] = __builtin_amdgcn_mfma_f32_16x16x32_bf16(aF[i], bF[j],
                                                              acc[i][j], 0, 0, 0);
    }
  }

  const int row0 = bm * 128 + wm * 64;
  const int col0 = bn * 128 + wn * 64;
  if (OUTMODE == 0) {
    unsigned short* C = (unsigned short*)Cv + sC * bz;
#pragma unroll
    for (int i = 0; i < 4; ++i)
#pragma unroll
      for (int j = 0; j < 4; ++j) {
        int col = col0 + j * 16 + l15;
        float bb = auxc[col];
#pragma unroll
        for (int r2 = 0; r2 < 4; ++r2) {
          int row = row0 + i * 16 + (lq << 2) + r2;
          C[(size_t)row * ldc + col] = f2bf(acc[i][j][r2] + bb);
        }
      }
  } else if (OUTMODE == 2) {
    unsigned short* C = (unsigned short*)Cv + sC * bz;
    float p[4][4];
#pragma unroll
    for (int i = 0; i < 4; ++i)
#pragma unroll
      for (int r2 = 0; r2 < 4; ++r2) p[i][r2] = 0.f;
#pragma unroll
    for (int i = 0; i < 4; ++i)
#pragma unroll
      for (int j = 0; j < 4; ++j) {
        int col = col0 + j * 16 + l15;
#pragma unroll
        for (int r2 = 0; r2 < 4; ++r2) {
          int row = row0 + i * 16 + (lq << 2) + r2;
          float e = __expf(acc[i][j][r2] * scale);
          C[(size_t)row * ldc + col] = f2bf(e);
          p[i][r2] += e;
        }
      }
    // reduce p over the 16 lanes sharing (lq): lane bits 0-3
#pragma unroll
    for (int i = 0; i < 4; ++i)
#pragma unroll
      for (int r2 = 0; r2 < 4; ++r2) {
        float v = p[i][r2];
        v += __shfl_xor(v, 1); v += __shfl_xor(v, 2);
        v += __shfl_xor(v, 4); v += __shfl_xor(v, 8);
        p[i][r2] = v;
      }
    __syncthreads();  // lA/lB reads done; safe to reuse barrier domain
    if (l15 == 0) {
#pragma unroll
      for (int i = 0; i < 4; ++i)
#pragma unroll
        for (int r2 = 0; r2 < 4; ++r2)
          sred[wn][wm * 64 + i * 16 + (lq << 2) + r2] = p[i][r2];
    }
    __syncthreads();
    if (t < 128) {
      float L = sred[0][t] + sred[1][t];
      auxw[((size_t)bz * 2048 + bm * 128 + t) * 16 + bn] = L;
    }
  } else {  // OUTMODE 3
    float* C = (float*)Cv + sC * bz;
#pragma unroll
    for (int i = 0; i < 4; ++i) {
      float il[4];
#pragma unroll
      for (int r2 = 0; r2 < 4; ++r2)
        il[r2] = auxc[(size_t)bz * 2048 + row0 + i * 16 + (lq << 2) + r2];
#pragma unroll
      for (int j = 0; j < 4; ++j) {
        int col = col0 + j * 16 + l15;
#pragma unroll
        for (int r2 = 0; r2 < 4; ++r2) {
          int row = row0 + i * 16 + (lq << 2) + r2;
          C[(size_t)row * ldc + col] = acc[i][j][r2] * il[r2];
        }
      }
    }
  }
}

// ---------------------------------------------------------------------------
// v part of qkv [16384][3072] (cols 2048+) -> vT [B][H][S] bf16
// ---------------------------------------------------------------------------
__global__ __launch_bounds__(1024) void transpose_v(const unsigned short* __restrict__ qkv,
                                                    unsigned short* __restrict__ vT) {
  __shared__ unsigned short tile[32][33];
  int s0 = blockIdx.x * 32, h0 = blockIdx.y * 32, b = blockIdx.z;
  int tx = threadIdx.x, ty = threadIdx.y;
  tile[ty][tx] = qkv[((size_t)b * 2048 + s0 + ty) * 3072 + 2048 + h0 + tx];
  __syncthreads();
  vT[((size_t)b * 1024 + h0 + ty) * 2048 + s0 + tx] = tile[tx][ty];
}

// ---------------------------------------------------------------------------
// Finish softmax: per row, L = sum of 16 partials; invL = 1/L; write probs
// fp32 = e(bf16) * invL.  One block (256 thr) per row.
// ---------------------------------------------------------------------------
__global__ __launch_bounds__(256) void finish_softmax(
    const float* __restrict__ Lpart, const unsigned short* __restrict__ pb,
    float* __restrict__ invL, float* __restrict__ probs) {
  const size_t row = blockIdx.x;
  const int t = threadIdx.x;
  __shared__ float sInv;
  if (t < 64) {
    float s = (t < 16) ? Lpart[row * 16 + t] : 0.f;
    s += __shfl_xor(s, 1); s += __shfl_xor(s, 2);
    s += __shfl_xor(s, 4); s += __shfl_xor(s, 8);
    if (t == 0) {
      float inv = 1.0f / s;
      sInv = inv;
      invL[row] = inv;
    }
  }
  __syncthreads();
  float inv = sInv;
  const ushort4* pv = (const ushort4*)(pb + row * 2048);
  float4* pr = (float4*)(probs + row * 2048);
  ushort4 a = pv[t * 2], b = pv[t * 2 + 1];
  float4 o0, o1;
  o0.x = bf2f(a.x) * inv; o0.y = bf2f(a.y) * inv;
  o0.z = bf2f(a.z) * inv; o0.w = bf2f(a.w) * inv;
  o1.x = bf2f(b.x) * inv; o1.y = bf2f(b.y) * inv;
  o1.z = bf2f(b.z) * inv; o1.w = bf2f(b.w) * inv;
  pr[t * 2] = o0; pr[t * 2 + 1] = o1;
}

// ---------------------------------------------------------------------------
extern "C" void kernel_launch(void* const* d_in, const int* in_sizes, int n_in,
                              void* d_out, int out_size, void* d_ws, size_t ws_size,
                              hipStream_t stream) {
  const float* x  = (const float*)d_in[0];
  const float* Wq = (const float*)d_in[1];
  const float* bq = (const float*)d_in[2];
  const float* Wk = (const float*)d_in[3];
  const float* bk = (const float*)d_in[4];
  const float* Wv = (const float*)d_in[5];
  const float* bv = (const float*)d_in[6];
  const float* Wl = (const float*)d_in[7];

  const int B = 8, S = 2048, H = 1024;
  float* out   = (float*)d_out;                     // [B,S,H]
  float* probs = (float*)d_out + (size_t)B * S * H; // [B,S,S]

  char* ws = (char*)d_ws;
  unsigned short* qkv  = (unsigned short*)(ws + 0);           // 100.7MB [16384][3072]
  unsigned short* pb   = (unsigned short*)(ws + 100663296);   // 67MB [B*S][2048] e=exp(s)
  unsigned short* xb   = (unsigned short*)(ws + 167772160);   // 33.5MB (dead after QKV GEMM)
  unsigned short* vT   = (unsigned short*)(ws + 167772160);   // 33.5MB overlays xb
  unsigned short* Wqkv = (unsigned short*)(ws + 201326592);   // 6.3MB [3072][1024]
  float* biasAll       = (float*)(ws + 207618048);            // 12KB
  float* Lpart         = (float*)(ws + 207630336);            // 1MB [16384][16]
  float* invL          = (float*)(ws + 208678912);            // 64KB [16384]

  prep_weights<<<1024, 128, 0, stream>>>(Wq, Wk, Wv, Wl, bq, bk, bv, Wqkv, biasAll);
  cast_bf16<<<16384, 256, 0, stream>>>((const float4*)x, (ushort4*)xb);

  // qkv = x @ Wqkv^T + biasAll   [16384][3072] bf16
  gemm_bt<0><<<dim3(24, 128, 1), 256, 0, stream>>>(xb, Wqkv, qkv, biasAll, nullptr,
      H, H, 3 * H, H, 1.f, 0, 0, 0);

  transpose_v<<<dim3(64, 32, 8), dim3(32, 32), 0, stream>>>(qkv, vT);

  // e = exp(q@k^T/32) bf16 -> pb, row-block partial sums -> Lpart
  gemm_bt<2><<<dim3(16, 16, 8), 256, 0, stream>>>(qkv, qkv + 1024, pb, nullptr, Lpart,
      3 * H, 3 * H, S, H, 1.0f / 32.0f, (size_t)S * 3 * H, (size_t)S * 3 * H, (size_t)S * S);

  finish_softmax<<<16384, 256, 0, stream>>>(Lpart, pb, invL, probs);

  // out = (e @ v) * invL[row]
  gemm_bt<3><<<dim3(8, 16, 8), 256, 0, stream>>>(pb, vT, out, invL, nullptr,
      S, S, H, S, 1.0f, (size_t)S * S, (size_t)H * S, (size_t)S * H);
}